// Round 6
// baseline (257.747 us; speedup 1.0000x reference)
//
#include <hip/hip_runtime.h>
#include <math.h>

#define H 32
#define S 64
#define K 64
#define B 32

__device__ __forceinline__ float gelu_f(float x) {
    return 0.5f * x * (1.0f + erff(x * 0.70710678118654752440f));
}

// Single-wave LDS ordering fence: waits LDS ops WITHOUT draining vmcnt
// (a full __syncthreads would drain the global W prefetch every step).
__device__ __forceinline__ void lds_fence() {
    asm volatile("s_waitcnt lgkmcnt(0)" ::: "memory");
}

// ws layout (floats):
// [0, 2080)              pe (65 x 32)
// [2080, 67616)          energies (32 x 64 x 32)
// [67616, 69664)         partials (2048)

__global__ void precompute_kernel(float* __restrict__ pe) {
    int t = blockIdx.x * 256 + threadIdx.x;
    if (t < 65 * 32) {
        int p = t >> 5, c = t & 31;
        int iq = c >> 1;
        double dt = pow(10000.0, (double)(2 * iq) / 32.0);
        float ang = (float)p * (float)dt;   // f32 rounding matches reference
        double v = (c & 1) ? cos((double)ang) : sin((double)ang);
        pe[t] = (float)v;
    }
}

// One single-wave block per batch row b. Barrier-free (lockstep wave),
// online-softmax pooling, depth-3 register prefetch of W that is never
// drained (no s_barrier => no vmcnt(0) flush).
__global__ __launch_bounds__(64) void chain_kernel(
    const int* __restrict__ neighbor_ids,
    const int* __restrict__ param_indices,
    const float* __restrict__ weights,
    const float* __restrict__ biases,
    const float* __restrict__ node_bias,
    const float* __restrict__ pe_g,
    const float* __restrict__ positions,
    float* __restrict__ energies) {
    int b = blockIdx.x;
    int l = threadIdx.x;      // 0..63
    int r = l >> 5;           // row-phase 0/1
    int d = l & 31;           // output column

    __shared__ float wbuf[2][H * H];     // double-buffered current W
    __shared__ float e_sh[2][H];
    __shared__ float bias_sh[S][H];
    __shared__ float pe_sh[(S + 1) * H];
    __shared__ float pos_sh[S];
    __shared__ int idx_sh[S];

    idx_sh[l] = param_indices[((size_t)(b * S + l)) * K];   // k=0 index per step
    pos_sh[l] = positions[l];
    for (int t = l; t < (S + 1) * H; t += 64) pe_sh[t] = pe_g[t];
    lds_fence();   // idx_sh/pe_sh/pos_sh visible

    for (int t = l; t < S * H; t += 64) {
        int row = t >> 5;
        bias_sh[row][t & 31] = biases[(size_t)idx_sh[row] * H + (t & 31)];
    }

    // depth-3 register prefetch of W (each lane carries 4 x float4 = 64B)
    float4 n0[4], n1[4], n2[4];
    {
        const float4* W0 = (const float4*)(weights + (size_t)idx_sh[0] * (H * H));
        const float4* W1 = (const float4*)(weights + (size_t)idx_sh[1] * (H * H));
        const float4* W2 = (const float4*)(weights + (size_t)idx_sh[2] * (H * H));
        #pragma unroll
        for (int j = 0; j < 4; ++j) { n0[j] = W0[j * 64 + l]; n1[j] = W1[j * 64 + l]; n2[j] = W2[j * 64 + l]; }
    }

    float init_e;
    {
        int nid = neighbor_ids[(size_t)b * S * K * 2];  // [b,0,0,0]
        init_e = gelu_f(0.03125f + node_bias[(size_t)nid * H + d] + pe_sh[d]);
    }

    // online softmax pooling state (per lane, column d; replicated across r)
    float m = -1e30f, ssum = 0.0f, A = 0.0f, nxtprev = 0.0f;

    for (int i = 0; i < S; ++i) {
        int cur = i & 1;
        #pragma unroll
        for (int j = 0; j < 4; ++j) ((float4*)wbuf[cur])[j * 64 + l] = n0[j];
        #pragma unroll
        for (int j = 0; j < 4; ++j) { n0[j] = n1[j]; n1[j] = n2[j]; }
        if (i + 3 < S) {
            const float4* Wn = (const float4*)(weights + (size_t)idx_sh[i + 3] * (H * H));
            #pragma unroll
            for (int j = 0; j < 4; ++j) n2[j] = Wn[j * 64 + l];
        }

        float e;
        if (i == 0) {
            e = init_e;
        } else {
            float p = pos_sh[i - 1];
            if (p > m) { float sc = expf(m - p); A *= sc; ssum *= sc; m = p; }
            float w = expf(p - m);
            A = fmaf(w, nxtprev, A);
            ssum += w;
            e = A / ssum;
        }
        if (r == 0) {
            energies[((size_t)(b * S + i)) * H + d] = e;
            e_sh[cur][d] = e;
        }
        lds_fence();   // wbuf[cur] + e_sh[cur] writes complete; vmcnt untouched

        float acc = 0.0f;
        #pragma unroll
        for (int hh = 0; hh < 16; ++hh) {
            int h = hh * 2 + r;
            acc = fmaf(e_sh[cur][h], wbuf[cur][h * 32 + d], acc);
        }
        acc += __shfl_xor(acc, 32, 64);
        nxtprev = gelu_f(acc + bias_sh[i][d] + pe_sh[(i + 1) * 32 + d]);
        // next step writes the OTHER buffer; step i+1's fence orders reuse of this one
    }
}

// One block (256 thr) per (b,i): K=64 gathered matvecs + logsumexp.
// Depth-2 software pipeline: while computing matrices (it), the W rows and
// biases of (it+1) are already in flight into registers -> loads never drain.
__global__ __launch_bounds__(256) void big_kernel(
    const int* __restrict__ param_indices,
    const float* __restrict__ weights,
    const float* __restrict__ biases,
    const float* __restrict__ pe_g,
    const float* __restrict__ energies,
    float* __restrict__ partials) {
    int bi = blockIdx.x;               // b*S + i
    int i = bi & 63;
    int tid = threadIdx.x;
    int wave = tid >> 6;               // 0..3
    int lane = tid & 63;
    int q = lane >> 4;                 // row-phase 0..3
    int dp = lane & 15;                // column-pair

    __shared__ float e_sh[H];
    __shared__ float en_sh[K];
    __shared__ int idx_sh[K];

    if (tid < H) e_sh[tid] = energies[(size_t)bi * H + tid];
    if (tid < K) idx_sh[tid] = param_indices[(size_t)bi * K + tid];
    float pex = pe_g[(i + 1) * H + 2 * dp];
    float pey = pe_g[(i + 1) * H + 2 * dp + 1];
    __syncthreads();

    float ereg[8];
    #pragma unroll
    for (int hh = 0; hh < 8; ++hh) ereg[hh] = e_sh[hh * 4 + q];

    int ka0 = wave * 16;   // this wave owns matrices ka0..ka0+7 and ka0+8..ka0+15

    float2 ca[8], cb[8], bca, bcb;
    {
        int ia = idx_sh[ka0], ib = idx_sh[ka0 + 8];
        const float2* Wa = (const float2*)(weights + (size_t)ia * (H * H));
        const float2* Wb = (const float2*)(weights + (size_t)ib * (H * H));
        #pragma unroll
        for (int hh = 0; hh < 8; ++hh) {
            ca[hh] = Wa[(hh * 4 + q) * 16 + dp];
            cb[hh] = Wb[(hh * 4 + q) * 16 + dp];
        }
        bca = *(const float2*)(biases + (size_t)ia * H + 2 * dp);
        bcb = *(const float2*)(biases + (size_t)ib * H + 2 * dp);
    }

    #pragma unroll
    for (int it = 0; it < 8; ++it) {
        float2 na[8], nb[8], bna, bnb;
        if (it < 7) {   // issue next iteration's loads before consuming current
            int ia = idx_sh[ka0 + it + 1], ib = idx_sh[ka0 + 8 + it + 1];
            const float2* Wa = (const float2*)(weights + (size_t)ia * (H * H));
            const float2* Wb = (const float2*)(weights + (size_t)ib * (H * H));
            #pragma unroll
            for (int hh = 0; hh < 8; ++hh) {
                na[hh] = Wa[(hh * 4 + q) * 16 + dp];
                nb[hh] = Wb[(hh * 4 + q) * 16 + dp];
            }
            bna = *(const float2*)(biases + (size_t)ia * H + 2 * dp);
            bnb = *(const float2*)(biases + (size_t)ib * H + 2 * dp);
        }

        float axa = 0, aya = 0, axb = 0, ayb = 0;
        #pragma unroll
        for (int hh = 0; hh < 8; ++hh) {
            axa = fmaf(ereg[hh], ca[hh].x, axa);
            aya = fmaf(ereg[hh], ca[hh].y, aya);
            axb = fmaf(ereg[hh], cb[hh].x, axb);
            ayb = fmaf(ereg[hh], cb[hh].y, ayb);
        }
        axa += __shfl_xor(axa, 16, 64); aya += __shfl_xor(aya, 16, 64);
        axb += __shfl_xor(axb, 16, 64); ayb += __shfl_xor(ayb, 16, 64);
        axa += __shfl_xor(axa, 32, 64); aya += __shfl_xor(aya, 32, 64);
        axb += __shfl_xor(axb, 32, 64); ayb += __shfl_xor(ayb, 32, 64);
        float v0a = gelu_f(axa + bca.x + pex);
        float v1a = gelu_f(aya + bca.y + pey);
        float v0b = gelu_f(axb + bcb.x + pex);
        float v1b = gelu_f(ayb + bcb.y + pey);
        float ssa = fmaf(v0a, v0a, v1a * v1a);
        float ssb = fmaf(v0b, v0b, v1b * v1b);
        #pragma unroll
        for (int mk = 8; mk; mk >>= 1) {
            ssa += __shfl_xor(ssa, mk, 64);
            ssb += __shfl_xor(ssb, mk, 64);
        }
        if (lane == 0) { en_sh[ka0 + it] = sqrtf(ssa); en_sh[ka0 + 8 + it] = sqrtf(ssb); }

        if (it < 7) {
            #pragma unroll
            for (int hh = 0; hh < 8; ++hh) { ca[hh] = na[hh]; cb[hh] = nb[hh]; }
            bca = bna; bcb = bnb;
        }
    }
    __syncthreads();

    // logsumexp over the 64 norms (wave 0 only)
    if (tid < K) {
        float en = en_sh[tid];
        float mm = en;
        #pragma unroll
        for (int mk = 32; mk; mk >>= 1) mm = fmaxf(mm, __shfl_xor(mm, mk, 64));
        float s = expf(en - mm);
        #pragma unroll
        for (int mk = 32; mk; mk >>= 1) s += __shfl_xor(s, mk, 64);
        if (tid == 0) partials[bi] = mm + logf(s) - en_sh[0];
    }
}

// Deterministic fixed-order reduction of the 2048 partials.
__global__ __launch_bounds__(256) void reduce_kernel(const float* __restrict__ partials,
                                                     float* __restrict__ out) {
    __shared__ float sh[256];
    int tid = threadIdx.x;
    float s = 0.0f;
    for (int j = 0; j < 8; ++j) s += partials[tid + j * 256];
    sh[tid] = s;
    __syncthreads();
    for (int ofs = 128; ofs; ofs >>= 1) {
        if (tid < ofs) sh[tid] += sh[tid + ofs];
        __syncthreads();
    }
    if (tid == 0) out[0] = sh[0] * (1.0f / 2048.0f);
}

extern "C" void kernel_launch(void* const* d_in, const int* in_sizes, int n_in,
                              void* d_out, int out_size, void* d_ws, size_t ws_size,
                              hipStream_t stream) {
    const int*   neighbor_ids  = (const int*)d_in[0];
    const int*   param_indices = (const int*)d_in[1];
    const float* weights       = (const float*)d_in[2];
    const float* biases        = (const float*)d_in[3];
    const float* node_bias     = (const float*)d_in[4];
    const float* positions     = (const float*)d_in[5];

    float* ws       = (float*)d_ws;
    float* pe       = ws;                    // 2080
    float* energies = ws + 2080;             // 65536
    float* partials = ws + 2080 + B * S * H; // 2048

    hipLaunchKernelGGL(precompute_kernel, dim3(9), dim3(256), 0, stream, pe);
    hipLaunchKernelGGL(chain_kernel, dim3(B), dim3(64), 0, stream,
                       neighbor_ids, param_indices, weights, biases, node_bias,
                       pe, positions, energies);
    // MEASUREMENT: big launched twice (idempotent). big_dur = total - 177.6us.
    hipLaunchKernelGGL(big_kernel, dim3(B * S), dim3(256), 0, stream,
                       param_indices, weights, biases, pe, energies, partials);
    hipLaunchKernelGGL(big_kernel, dim3(B * S), dim3(256), 0, stream,
                       param_indices, weights, biases, pe, energies, partials);
    hipLaunchKernelGGL(reduce_kernel, dim3(1), dim3(256), 0, stream,
                       partials, (float*)d_out);
}

// Round 7
// 135.148 us; speedup vs baseline: 1.9072x; 1.9072x over previous
//
#include <hip/hip_runtime.h>
#include <math.h>

#define H 32
#define S 64
#define K 64
#define B 32

__device__ __forceinline__ float gelu_f(float x) {
    return 0.5f * x * (1.0f + erff(x * 0.70710678118654752440f));
}

// Single-wave LDS ordering fence: waits LDS ops WITHOUT draining vmcnt.
__device__ __forceinline__ void lds_fence() {
    asm volatile("s_waitcnt lgkmcnt(0)" ::: "memory");
}

__device__ __forceinline__ float bcast_lane(float v, int lane) {
    return __uint_as_float(__builtin_amdgcn_readlane(__float_as_uint(v), lane));
}

// ws layout (floats):
// [0, 2080)              pe (65 x 32)
// [2080, 67616)          energies (32 x 64 x 32)
// [67616, 69664)         partials (2048)

__global__ void precompute_kernel(float* __restrict__ pe) {
    int t = blockIdx.x * 256 + threadIdx.x;
    if (t < 65 * 32) {
        int p = t >> 5, c = t & 31;
        int iq = c >> 1;
        double dt = pow(10000.0, (double)(2 * iq) / 32.0);
        float ang = (float)p * (float)dt;   // f32 rounding matches reference
        double v = (c & 1) ? cos((double)ang) : sin((double)ang);
        pe[t] = (float)v;
    }
}

// One single-wave block per batch row b. ALL-REGISTER step loop:
// W held in 4 named register buffers (depth-4 prefetch, statically indexed),
// e broadcast via readlane, halves combined with one shfl_xor. No LDS writes,
// no fences, no barriers inside the loop.
__global__ __launch_bounds__(64) void chain_kernel(
    const int* __restrict__ neighbor_ids,
    const int* __restrict__ param_indices,
    const float* __restrict__ weights,
    const float* __restrict__ biases,
    const float* __restrict__ node_bias,
    const float* __restrict__ pe_g,
    const float* __restrict__ positions,
    float* __restrict__ energies) {
    int b = blockIdx.x;
    int l = threadIdx.x;      // 0..63
    int r = l >> 5;           // row-phase 0/1 (h-halves)
    int d = l & 31;           // output column

    __shared__ int idx_sh[S];
    __shared__ float pos_sh[S];
    __shared__ float pe_sh[(S + 1) * H];
    __shared__ float bias_sh[S * H];

    idx_sh[l] = param_indices[((size_t)(b * S + l)) * K];   // k=0 index per step
    pos_sh[l] = positions[l];
    for (int t = l; t < (S + 1) * H; t += 64) pe_sh[t] = pe_g[t];
    lds_fence();   // idx/pos/pe visible

    for (int t = l; t < S * H; t += 64)
        bias_sh[t] = biases[(size_t)idx_sh[t >> 5] * H + (t & 31)];

    float init_e;
    {
        int nid = neighbor_ids[(size_t)b * S * K * 2];  // [b,0,0,0]
        init_e = gelu_f(0.03125f + node_bias[(size_t)nid * H + d] + pe_sh[d]);
    }
    lds_fence();   // bias_sh visible

    // Register W buffers: wb[j] = W[r*16+j][d] for the step this buffer holds.
    float w0[16], w1[16], w2[16], w3[16];
    const int rowoff = r * 16;

    auto loadW = [&](float (&wb)[16], int step) {
        const float* Wp = weights + (size_t)idx_sh[step] * (H * H) + (size_t)rowoff * H + d;
        #pragma unroll
        for (int j = 0; j < 16; ++j) wb[j] = Wp[j * H];   // column-d, stride 128B
    };
    loadW(w0, 0); loadW(w1, 1); loadW(w2, 2); loadW(w3, 3);

    // online softmax pooling state (per lane, column d; replicated across r)
    float m = -1e30f, ssum = 0.0f, A = 0.0f, nxtprev = 0.0f;

    auto step = [&](float (&wb)[16], int i) {
        float e;
        if (i == 0) {
            e = init_e;
        } else {
            float p = pos_sh[i - 1];
            if (p > m) { float sc = expf(m - p); A *= sc; ssum *= sc; m = p; }
            float wgt = expf(p - m);
            A = fmaf(wgt, nxtprev, A);
            ssum += wgt;
            e = A / ssum;
        }
        if (r == 0) energies[((size_t)(b * S + i)) * H + d] = e;

        float acc = 0.0f;
        #pragma unroll
        for (int j = 0; j < 16; ++j) {
            float e0 = bcast_lane(e, j);        // e[j]      (held in lane j)
            float e1 = bcast_lane(e, 16 + j);   // e[16+j]
            acc = fmaf(r ? e1 : e0, wb[j], acc);
        }
        acc += __shfl_xor(acc, 32, 64);          // combine h-halves
        nxtprev = gelu_f(acc + bias_sh[i * H + d] + pe_sh[(i + 1) * H + d]);
        if (i + 4 < S) loadW(wb, i + 4);         // refill this buffer, 4 ahead
    };

    #pragma unroll
    for (int ii = 0; ii < S; ii += 4) {
        step(w0, ii);
        step(w1, ii + 1);
        step(w2, ii + 2);
        step(w3, ii + 3);
    }
}

// One block (256 thr) per (b,i): K=64 gathered matvecs + logsumexp.
__global__ __launch_bounds__(256) void big_kernel(
    const int* __restrict__ param_indices,
    const float* __restrict__ weights,
    const float* __restrict__ biases,
    const float* __restrict__ pe_g,
    const float* __restrict__ energies,
    float* __restrict__ partials) {
    int bi = blockIdx.x;               // b*S + i
    int i = bi & 63;
    int tid = threadIdx.x;
    int wave = tid >> 6;               // 0..3
    int lane = tid & 63;
    int q = lane >> 4;                 // row-phase 0..3
    int dp = lane & 15;                // column-pair

    __shared__ float e_sh[H];
    __shared__ float en_sh[K];
    __shared__ int idx_sh[K];

    if (tid < H) e_sh[tid] = energies[(size_t)bi * H + tid];
    if (tid < K) idx_sh[tid] = param_indices[(size_t)bi * K + tid];
    float pex = pe_g[(i + 1) * H + 2 * dp];
    float pey = pe_g[(i + 1) * H + 2 * dp + 1];
    __syncthreads();

    float ereg[8];
    #pragma unroll
    for (int hh = 0; hh < 8; ++hh) ereg[hh] = e_sh[hh * 4 + q];

    int ka0 = wave * 16;   // this wave owns matrices ka0..ka0+7 and ka0+8..ka0+15

    float2 ca[8], cb[8], bca, bcb;
    {
        int ia = idx_sh[ka0], ib = idx_sh[ka0 + 8];
        const float2* Wa = (const float2*)(weights + (size_t)ia * (H * H));
        const float2* Wb = (const float2*)(weights + (size_t)ib * (H * H));
        #pragma unroll
        for (int hh = 0; hh < 8; ++hh) {
            ca[hh] = Wa[(hh * 4 + q) * 16 + dp];
            cb[hh] = Wb[(hh * 4 + q) * 16 + dp];
        }
        bca = *(const float2*)(biases + (size_t)ia * H + 2 * dp);
        bcb = *(const float2*)(biases + (size_t)ib * H + 2 * dp);
    }

    #pragma unroll
    for (int it = 0; it < 8; ++it) {
        float2 na[8], nb[8], bna, bnb;
        if (it < 7) {   // issue next iteration's loads before consuming current
            int ia = idx_sh[ka0 + it + 1], ib = idx_sh[ka0 + 8 + it + 1];
            const float2* Wa = (const float2*)(weights + (size_t)ia * (H * H));
            const float2* Wb = (const float2*)(weights + (size_t)ib * (H * H));
            #pragma unroll
            for (int hh = 0; hh < 8; ++hh) {
                na[hh] = Wa[(hh * 4 + q) * 16 + dp];
                nb[hh] = Wb[(hh * 4 + q) * 16 + dp];
            }
            bna = *(const float2*)(biases + (size_t)ia * H + 2 * dp);
            bnb = *(const float2*)(biases + (size_t)ib * H + 2 * dp);
        }

        float axa = 0, aya = 0, axb = 0, ayb = 0;
        #pragma unroll
        for (int hh = 0; hh < 8; ++hh) {
            axa = fmaf(ereg[hh], ca[hh].x, axa);
            aya = fmaf(ereg[hh], ca[hh].y, aya);
            axb = fmaf(ereg[hh], cb[hh].x, axb);
            ayb = fmaf(ereg[hh], cb[hh].y, ayb);
        }
        axa += __shfl_xor(axa, 16, 64); aya += __shfl_xor(aya, 16, 64);
        axb += __shfl_xor(axb, 16, 64); ayb += __shfl_xor(ayb, 16, 64);
        axa += __shfl_xor(axa, 32, 64); aya += __shfl_xor(aya, 32, 64);
        axb += __shfl_xor(axb, 32, 64); ayb += __shfl_xor(ayb, 32, 64);
        float v0a = gelu_f(axa + bca.x + pex);
        float v1a = gelu_f(aya + bca.y + pey);
        float v0b = gelu_f(axb + bcb.x + pex);
        float v1b = gelu_f(ayb + bcb.y + pey);
        float ssa = fmaf(v0a, v0a, v1a * v1a);
        float ssb = fmaf(v0b, v0b, v1b * v1b);
        #pragma unroll
        for (int mk = 8; mk; mk >>= 1) {
            ssa += __shfl_xor(ssa, mk, 64);
            ssb += __shfl_xor(ssb, mk, 64);
        }
        if (lane == 0) { en_sh[ka0 + it] = sqrtf(ssa); en_sh[ka0 + 8 + it] = sqrtf(ssb); }

        if (it < 7) {
            #pragma unroll
            for (int hh = 0; hh < 8; ++hh) { ca[hh] = na[hh]; cb[hh] = nb[hh]; }
            bca = bna; bcb = bnb;
        }
    }
    __syncthreads();

    // logsumexp over the 64 norms (wave 0 only)
    if (tid < K) {
        float en = en_sh[tid];
        float mm = en;
        #pragma unroll
        for (int mk = 32; mk; mk >>= 1) mm = fmaxf(mm, __shfl_xor(mm, mk, 64));
        float s = expf(en - mm);
        #pragma unroll
        for (int mk = 32; mk; mk >>= 1) s += __shfl_xor(s, mk, 64);
        if (tid == 0) partials[bi] = mm + logf(s) - en_sh[0];
    }
}

// Deterministic fixed-order reduction of the 2048 partials.
__global__ __launch_bounds__(256) void reduce_kernel(const float* __restrict__ partials,
                                                     float* __restrict__ out) {
    __shared__ float sh[256];
    int tid = threadIdx.x;
    float s = 0.0f;
    for (int j = 0; j < 8; ++j) s += partials[tid + j * 256];
    sh[tid] = s;
    __syncthreads();
    for (int ofs = 128; ofs; ofs >>= 1) {
        if (tid < ofs) sh[tid] += sh[tid + ofs];
        __syncthreads();
    }
    if (tid == 0) out[0] = sh[0] * (1.0f / 2048.0f);
}

extern "C" void kernel_launch(void* const* d_in, const int* in_sizes, int n_in,
                              void* d_out, int out_size, void* d_ws, size_t ws_size,
                              hipStream_t stream) {
    const int*   neighbor_ids  = (const int*)d_in[0];
    const int*   param_indices = (const int*)d_in[1];
    const float* weights       = (const float*)d_in[2];
    const float* biases        = (const float*)d_in[3];
    const float* node_bias     = (const float*)d_in[4];
    const float* positions     = (const float*)d_in[5];

    float* ws       = (float*)d_ws;
    float* pe       = ws;                    // 2080
    float* energies = ws + 2080;             // 65536
    float* partials = ws + 2080 + B * S * H; // 2048

    hipLaunchKernelGGL(precompute_kernel, dim3(9), dim3(256), 0, stream, pe);
    hipLaunchKernelGGL(chain_kernel, dim3(B), dim3(64), 0, stream,
                       neighbor_ids, param_indices, weights, biases, node_bias,
                       pe, positions, energies);
    hipLaunchKernelGGL(big_kernel, dim3(B * S), dim3(256), 0, stream,
                       param_indices, weights, biases, pe, energies, partials);
    hipLaunchKernelGGL(reduce_kernel, dim3(1), dim3(256), 0, stream,
                       partials, (float*)d_out);
}